// Round 6
// baseline (236.953 us; speedup 1.0000x reference)
//
#include <hip/hip_runtime.h>
#include <hip/hip_bf16.h>

// ---------------------------------------------------------------------------
// Reformulation: Rad[z,:] = t*A[iv] + B[iv] (piecewise-linear MLP) =>
//   C[z,c] = sum_m coef[z,m] * T[iv_z][m][c],  K = 18 (not 864!)
//   coef[m<9] = Ysh[y=m]*t, coef[9+y] = Ysh[y]
//   T[iv][y][c]   = QA[iv,y,c] = sum_w A[iv,w]*Q[c,y,w]   (precomputed)
//   T[iv][9+y][c] = QB[iv,y,c] = sum_w B[iv,w]*Q[c,y,w]
// 604 MFLOP total -> memory-bound on the 64MB output write (~10us floor).
// Points are counting-sorted by iv so each k_out block has uniform iv:
// stage T[iv] (16KB) once, 16x16x32 bf16 MFMA (K zero-padded 18->32),
// scatter-store 1KB/point contiguous rows.
// ---------------------------------------------------------------------------

typedef __attribute__((ext_vector_type(8))) short bfrag;   // 8 x bf16
typedef __attribute__((ext_vector_type(4))) float fx4;     // 16x16 accum

// workspace byte offsets
#define WS_TB   0           // f32[128] sorted breakpoints (+inf pad)
#define WS_AT   512         // f32[129*96]
#define WS_BT   50048       // f32[129*96]
#define WS_QT   99584       // bf16[129][16cb][4g][16c][8e] = 2,064,384 B
#define WS_IVZ  2164224     // u32[65536]
#define WS_PERM 2426368     // u32[65536]
#define WS_HIST 2688512     // u32[129] (pad to 640)
#define WS_CUR  2689152     // u32[129] (pad to 640)
#define WS_BTAB 2689792     // uint4[1153] = 18448 B   (end ~2.71 MB)
#define NCHUNKS 1153        // 65536/64 + 129 upper bound

__device__ inline unsigned short f2bf(float f) {   // RNE float->bf16
  union { float f; unsigned int u; } v; v.f = f;
  unsigned int r = v.u + 0x7FFFu + ((v.u >> 16) & 1u);
  return (unsigned short)(r >> 16);
}
__device__ inline unsigned int pack2(float a, float b) {
  return (unsigned int)f2bf(a) | ((unsigned int)f2bf(b) << 16);
}
__device__ inline void gl_lds16(const void* g, void* l) {
  __builtin_amdgcn_global_load_lds(
      (const __attribute__((address_space(1))) unsigned int*)g,
      (__attribute__((address_space(3))) unsigned int*)l, 16, 0, 0);
}

// ---------------------------------------------------------------------------
// K1: piecewise-linear tables (f32). One block, 128 threads.
// ---------------------------------------------------------------------------
__global__ void k_tables(const float* __restrict__ W1, const float* __restrict__ b1,
                         const float* __restrict__ W2, const float* __restrict__ b2,
                         float* __restrict__ tb, float* __restrict__ At,
                         float* __restrict__ Bt) {
  __shared__ float w2_s[128 * 96];
  __shared__ float val_s[128], stb_s[128], w1_s[128], b1_s[128];
  __shared__ int   perm_s[128];
  const int tid = threadIdx.x;
  for (int i = tid; i < 128 * 96; i += 128) w2_s[i] = W2[i];
  const float INF = __builtin_inff();
  float w1 = W1[tid], b1v = b1[tid];
  w1_s[tid] = w1; b1_s[tid] = b1v;
  float tj = -b1v / w1;
  bool valid = (w1 != 0.0f) && (tj > 0.0f);
  val_s[tid] = valid ? tj : INF;
  __syncthreads();
  {
    float v = val_s[tid];
    int rank = 0;
    for (int m = 0; m < 128; ++m) {
      float vm = val_s[m];
      rank += (vm < v || (vm == v && m < tid)) ? 1 : 0;
    }
    stb_s[rank] = v; perm_s[rank] = tid;
  }
  __syncthreads();
  tb[tid] = stb_s[tid];
  if (tid < 96) {
    float s0  = stb_s[0];
    float tm0 = (s0 == INF) ? 1.0f : 0.5f * s0;
    float sa = 0.f, sb = 0.f;
#pragma unroll 8
    for (int j = 0; j < 128; ++j) {
      float on = (tm0 * w1_s[j] + b1_s[j] > 0.0f) ? 1.f : 0.f;
      float w2 = on * w2_s[j * 96 + tid];
      sa += w2 * w1_s[j]; sb += w2 * b1_s[j];
    }
    float b2v = b2[tid];
    At[tid] = sa; Bt[tid] = sb + b2v;
#pragma unroll 8
    for (int s = 0; s < 128; ++s) {
      int   j    = perm_s[s];
      float live = (stb_s[s] < INF) ? 1.f : 0.f;
      float sgn  = (w1_s[j] > 0.f) ? live : -live;
      float w2   = sgn * w2_s[j * 96 + tid];
      sa += w2 * w1_s[j]; sb += w2 * b1_s[j];
      At[(s + 1) * 96 + tid] = sa; Bt[(s + 1) * 96 + tid] = sb + b2v;
    }
  }
}

// ---------------------------------------------------------------------------
// K2: QT table. grid (129 iv, 9 y), 256 thr (c). MFMA-subtiled bf16 layout:
// byte(iv,c,k) = iv*16384 + (c>>4)*1024 + (k>>3)*256 + (c&15)*16 + (k&7)*2
// k = y (QA), 9+y (QB); k in [18,32) zeroed by y==0 blocks.
// ---------------------------------------------------------------------------
__global__ void k_qt(const float* __restrict__ Q, const float* __restrict__ At,
                     const float* __restrict__ Bt, unsigned short* __restrict__ qt) {
  __shared__ float at_s[96], bt_s[96];
  const int iv = blockIdx.x, y = blockIdx.y, c = threadIdx.x;
  if (c < 96) { at_s[c] = At[iv * 96 + c]; bt_s[c] = Bt[iv * 96 + c]; }
  __syncthreads();
  const float* q = Q + (size_t)c * 864 + y * 96;
  float qa = 0.f, qb = 0.f;
#pragma unroll
  for (int w4 = 0; w4 < 24; ++w4) {
    float4 qv = *(const float4*)(q + w4 * 4);
    qa += qv.x * at_s[w4*4+0] + qv.y * at_s[w4*4+1] + qv.z * at_s[w4*4+2] + qv.w * at_s[w4*4+3];
    qb += qv.x * bt_s[w4*4+0] + qv.y * bt_s[w4*4+1] + qv.z * bt_s[w4*4+2] + qv.w * bt_s[w4*4+3];
  }
  char* base = (char*)qt + (size_t)iv * 16384 + (c >> 4) * 1024 + (c & 15) * 16;
  const int ka = y, kb = 9 + y;
  *(unsigned short*)(base + (ka >> 3) * 256 + (ka & 7) * 2) = f2bf(qa);
  *(unsigned short*)(base + (kb >> 3) * 256 + (kb & 7) * 2) = f2bf(qb);
  if (y == 0) {
#pragma unroll
    for (int k = 18; k < 32; ++k)
      *(unsigned short*)(base + (k >> 3) * 256 + (k & 7) * 2) = 0;
  }
}

// ---------------------------------------------------------------------------
// K3: per-point iv + histogram. grid 256 x 256 thr.
// ---------------------------------------------------------------------------
__global__ void k_iv(const float* __restrict__ r, const float* __restrict__ tbg,
                     unsigned int* __restrict__ ivz, unsigned int* __restrict__ hist) {
  __shared__ float tb_s[128];
  __shared__ unsigned int h_s[129];
  const int tid = threadIdx.x;
  const int z = blockIdx.x * 256 + tid;
  if (tid < 128) tb_s[tid] = tbg[tid];
  if (tid < 129) h_s[tid] = 0;
  __syncthreads();
  float rx = r[z * 3 + 0], ry = r[z * 3 + 1], rz = r[z * 3 + 2];
  float rad = sqrtf(rx * rx + ry * ry + rz * rz);
  int lo = 0, hi = 128;
  while (lo < hi) { int mid = (lo + hi) >> 1;
                    if (tb_s[mid] < rad) lo = mid + 1; else hi = mid; }
  ivz[z] = (unsigned)lo | (rad > 0.f ? 0u : 0x80000000u);
  atomicAdd(&h_s[lo], 1u);
  __syncthreads();
  if (tid < 129 && h_s[tid]) atomicAdd(&hist[tid], h_s[tid]);
}

// ---------------------------------------------------------------------------
// K4: scan + cursor + block table. 1 block, 256 thr.
// ---------------------------------------------------------------------------
__global__ void k_scan(const unsigned int* __restrict__ hist,
                       unsigned int* __restrict__ cursor, uint4* __restrict__ btab) {
  __shared__ unsigned int h_s[129], st_s[130], eo_s[130];
  const int tid = threadIdx.x;
  if (tid < 129) h_s[tid] = hist[tid];
  __syncthreads();
  if (tid == 0) {
    unsigned s = 0, e = 0;
    for (int i = 0; i < 129; ++i) {
      st_s[i] = s; eo_s[i] = e;
      s += h_s[i]; e += (h_s[i] + 63) >> 6;
    }
    st_s[129] = s; eo_s[129] = e;
  }
  __syncthreads();
  if (tid < 129) cursor[tid] = st_s[tid];
  const unsigned total = eo_s[129];
  for (unsigned e = tid; e < NCHUNKS; e += 256) {
    uint4 ent = make_uint4(0, 0, 0, 0);
    if (e < total) {
      int lo = 0, hi = 128;
      while (lo < hi) { int mid = (lo + hi + 1) >> 1;
                        if (eo_s[mid] <= e) lo = mid; else hi = mid - 1; }
      unsigned chunk = e - eo_s[lo];
      unsigned nn = h_s[lo];
      unsigned cnt = nn - chunk * 64; if (cnt > 64) cnt = 64;
      ent = make_uint4((unsigned)lo, st_s[lo] + chunk * 64, cnt, 0);
    }
    btab[e] = ent;
  }
}

// ---------------------------------------------------------------------------
// K5: scatter. grid 256 x 256 thr.
// ---------------------------------------------------------------------------
__global__ void k_scatter(const unsigned int* __restrict__ ivz,
                          unsigned int* __restrict__ cursor,
                          unsigned int* __restrict__ perm) {
  const int z = blockIdx.x * 256 + threadIdx.x;
  unsigned u = ivz[z];
  unsigned iv = u & 255u;
  unsigned pos = atomicAdd(&cursor[iv], 1u);
  perm[pos] = (unsigned)z | (u & 0x80000000u);
}

// ---------------------------------------------------------------------------
// K6: output. grid NCHUNKS x 256 thr (4 waves). Block = one (iv, 64-pt chunk).
// T_s staged via global_load_lds; coef built in-thread; one K=32 MFMA pass;
// scatter-store rows. Subtiled LDS: frag read = base + wave-uniform + lane*16
// -> conflict-free ds_read_b128 on both operands.
// ---------------------------------------------------------------------------
__global__ __launch_bounds__(256)
void k_out(const float* __restrict__ r, const unsigned short* __restrict__ qt,
           const unsigned int* __restrict__ perm, const uint4* __restrict__ btab,
           const float* __restrict__ K0, float* __restrict__ out) {
  __shared__ unsigned short T_s[8192];     // 16 KB: [cb(16)][g(4)][c16(16)][e(8)]
  __shared__ unsigned short coef_s[2048];  //  4 KB: [rb(4)][g(4)][r16(16)][e(8)]
  __shared__ unsigned int z_s[64];
  __shared__ unsigned int mk_s[64];

  const uint4 ent = btab[blockIdx.x];
  const unsigned iv = ent.x, base = ent.y, cnt = ent.z;
  if (cnt == 0) return;

  const int tid  = threadIdx.x;
  const int lane = tid & 63;
  const int wave = tid >> 6;
  const int lg   = lane >> 4;
  const int l15  = lane & 15;

  // stage T[iv] (16 KB) via async global->LDS
  {
    const char* src = (const char*)qt + (size_t)iv * 16384 + wave * 1024 + lane * 16;
    char* dst = (char*)T_s + wave * 1024;
#pragma unroll
    for (int i = 0; i < 4; ++i) gl_lds16(src + i * 4096, dst + i * 4096);
  }

  // coef staging: thread j < 64 handles one point
  if (tid < 64) {
    const int j = tid;
    unsigned pz = perm[base + (j < (int)cnt ? j : 0)];
    unsigned z = pz & 0x7FFFFFFFu;
    z_s[j] = z; mk_s[j] = pz >> 31;
    const float* rg = r + (size_t)z * 3;
    float rx = rg[0], ry = rg[1], rz = rg[2];
    float rad = sqrtf(rx * rx + ry * ry + rz * rz);
    float inv = (rad > 0.f) ? (1.0f / rad) : 1.0f;
    float x = rx * inv, y = ry * inv, zc = rz * inv;
    const float SQ3 = 1.7320508075688772f, SQ5 = 2.2360679774997896f,
                SQ15 = 3.872983346207417f;
    float ys[9];
    ys[0] = 1.f;
    ys[1] = SQ3 * y;  ys[2] = SQ3 * zc;  ys[3] = SQ3 * x;
    ys[4] = SQ15 * x * y;  ys[5] = SQ15 * y * zc;
    ys[6] = 0.5f * SQ5 * (3.f * zc * zc - 1.f);
    ys[7] = SQ15 * x * zc;
    ys[8] = 0.5f * SQ15 * (x * x - y * y);
    float cf[18];
#pragma unroll
    for (int m = 0; m < 9; ++m) { cf[m] = ys[m] * rad; cf[9 + m] = ys[m]; }
    char* cbp = (char*)coef_s + (j >> 4) * 1024 + (j & 15) * 16;
#pragma unroll
    for (int g = 0; g < 4; ++g)
#pragma unroll
      for (int p = 0; p < 4; ++p) {
        const int k0 = g * 8 + p * 2, k1 = k0 + 1;
        float v0 = (k0 < 18) ? cf[k0] : 0.f;
        float v1 = (k1 < 18) ? cf[k1] : 0.f;
        *(unsigned int*)(cbp + g * 256 + p * 4) = pack2(v0, v1);
      }
  }
  __syncthreads();   // T_s (vmcnt) + coef_s published

  // MFMA: wave handles rows [wave*16, wave*16+16) x all 256 cols
  fx4 acc[16];
#pragma unroll
  for (int cb2 = 0; cb2 < 16; ++cb2)
#pragma unroll
    for (int e = 0; e < 4; ++e) acc[cb2][e] = 0.f;

  const bfrag a = *(const bfrag*)((char*)coef_s + wave * 1024 + lg * 256 + l15 * 16);
#pragma unroll
  for (int cb2 = 0; cb2 < 16; ++cb2) {
    const bfrag b = *(const bfrag*)((char*)T_s + cb2 * 1024 + lg * 256 + l15 * 16);
    acc[cb2] = __builtin_amdgcn_mfma_f32_16x16x32_bf16(a, b, acc[cb2], 0, 0, 0);
  }

  // store: C/D 16x16 map: col = lane&15, row = (lane>>4)*4 + q
  float k0v[16];
#pragma unroll
  for (int cb2 = 0; cb2 < 16; ++cb2) k0v[cb2] = K0[cb2 * 16 + l15];
#pragma unroll
  for (int q = 0; q < 4; ++q) {
    const int br = wave * 16 + lg * 4 + q;
    if (br < (int)cnt) {
      const unsigned z = z_s[br];
      const bool mq = mk_s[br] != 0;
      float* ob = out + (size_t)z * 256 + l15;
#pragma unroll
      for (int cb2 = 0; cb2 < 16; ++cb2)
        ob[cb2 * 16] = mq ? k0v[cb2] : acc[cb2][q];
    }
  }
}

// ---------------------------------------------------------------------------
extern "C" void kernel_launch(void* const* d_in, const int* in_sizes, int n_in,
                              void* d_out, int out_size, void* d_ws, size_t ws_size,
                              hipStream_t stream) {
  const float* r  = (const float*)d_in[0];
  const float* Q  = (const float*)d_in[1];
  const float* W1 = (const float*)d_in[2];
  const float* b1 = (const float*)d_in[3];
  const float* W2 = (const float*)d_in[4];
  const float* b2 = (const float*)d_in[5];
  const float* K0 = (const float*)d_in[6];
  float* out = (float*)d_out;
  char* ws = (char*)d_ws;
  float* tb = (float*)(ws + WS_TB);
  float* At = (float*)(ws + WS_AT);
  float* Bt = (float*)(ws + WS_BT);
  unsigned short* qt = (unsigned short*)(ws + WS_QT);
  unsigned int* ivz  = (unsigned int*)(ws + WS_IVZ);
  unsigned int* perm = (unsigned int*)(ws + WS_PERM);
  unsigned int* hist = (unsigned int*)(ws + WS_HIST);
  unsigned int* cur  = (unsigned int*)(ws + WS_CUR);
  uint4* btab        = (uint4*)(ws + WS_BTAB);

  hipMemsetAsync(hist, 0, 129 * sizeof(unsigned int), stream);
  hipLaunchKernelGGL(k_tables, dim3(1), dim3(128), 0, stream, W1, b1, W2, b2, tb, At, Bt);
  hipLaunchKernelGGL(k_qt, dim3(129, 9), dim3(256), 0, stream, Q, At, Bt, qt);
  hipLaunchKernelGGL(k_iv, dim3(256), dim3(256), 0, stream, r, tb, ivz, hist);
  hipLaunchKernelGGL(k_scan, dim3(1), dim3(256), 0, stream, hist, cur, btab);
  hipLaunchKernelGGL(k_scatter, dim3(256), dim3(256), 0, stream, ivz, cur, perm);
  hipLaunchKernelGGL(k_out, dim3(NCHUNKS), dim3(256), 0, stream, r, qt, perm, btab, K0, out);
}

// Round 9
// 77.059 us; speedup vs baseline: 3.0750x; 3.0750x over previous
//
#include <hip/hip_runtime.h>
#include <hip/hip_bf16.h>

// ---------------------------------------------------------------------------
// Reformulation: Rad[z,:] = t*A[iv] + B[iv] (piecewise-linear MLP) =>
//   C[z,c] = sum_m coef[z,m] * T[iv_z][m][c],  K = 18 (not 864)
//   coef[m<9] = Ysh[y=m]*t, coef[9+y] = Ysh[y]
//   T[iv][y][c] = sum_w A[iv,w]*Q[c,y,w];  T[iv][9+y][c] = sum_w B[iv,w]*Q[c,y,w]
// Points counting-sorted by iv, deterministic, NO global atomics.
// ROUND-9 FIX: qt table is 129*16384 = 2,113,536 B (previous rounds allocated
// 2,064,384 = 126*16384 -- iv>=126 overflowed into ivz; round 6 survived only
// because k_iv rewrote ivz afterwards; fused k_mid made it a live race).
// Peak ws = 2,672,384 B < 2,708,240 proven safe in round 6.
// ---------------------------------------------------------------------------

typedef __attribute__((ext_vector_type(8))) short bfrag;   // 8 x bf16
typedef __attribute__((ext_vector_type(4))) float fx4;     // 16x16 accum

// workspace byte offsets
#define WS_TB   0           // f32[128]
#define WS_AT   512         // f32[129*96] = 49536            (dead after k_mid)
#define WS_BT   50048       // f32[129*96] = 49536            (dead after k_mid)
#define WS_BOFF 512         // OVERLAY: u32[64][132] = 33792  (k_scan -> k_scatter)
#define WS_BTAB 34304       // OVERLAY: uint4[1153] = 18448   (k_scan -> k_out, ends 52752)
#define WS_QT   99584       // bf16[129][16384B] = 2113536, ends 2213120
#define WS_IVZ  2213120     // u16[65536] = 131072, ends 2344192
#define WS_PERM 2344192     // u32[65536] = 262144, ends 2606336
#define WS_BH   2606336     // u16[129][256] = 66048, ends 2672384 (peak)
#define NCHUNKS 1153        // 65536/64 + 129 upper bound
#define NQTBLK  1161        // 129 iv * 9 y

__device__ inline unsigned short f2bf(float f) {   // RNE float->bf16
  union { float f; unsigned int u; } v; v.f = f;
  unsigned int r = v.u + 0x7FFFu + ((v.u >> 16) & 1u);
  return (unsigned short)(r >> 16);
}
__device__ inline unsigned int pack2(float a, float b) {
  return (unsigned int)f2bf(a) | ((unsigned int)f2bf(b) << 16);
}
__device__ inline void gl_lds16(const void* g, void* l) {
  __builtin_amdgcn_global_load_lds(
      (const __attribute__((address_space(1))) unsigned int*)g,
      (__attribute__((address_space(3))) unsigned int*)l, 16, 0, 0);
}

// ---------------------------------------------------------------------------
// K1: piecewise-linear tables (f32). One block, 128 threads.
// ---------------------------------------------------------------------------
__global__ void k_tables(const float* __restrict__ W1, const float* __restrict__ b1,
                         const float* __restrict__ W2, const float* __restrict__ b2,
                         float* __restrict__ tb, float* __restrict__ At,
                         float* __restrict__ Bt) {
  __shared__ float w2_s[128 * 96];
  __shared__ float val_s[128], stb_s[128], w1_s[128], b1_s[128];
  __shared__ int   perm_s[128];
  const int tid = threadIdx.x;
  for (int i = tid; i < 128 * 96; i += 128) w2_s[i] = W2[i];
  const float INF = __builtin_inff();
  float w1 = W1[tid], b1v = b1[tid];
  w1_s[tid] = w1; b1_s[tid] = b1v;
  float tj = -b1v / w1;
  bool valid = (w1 != 0.0f) && (tj > 0.0f);
  val_s[tid] = valid ? tj : INF;
  __syncthreads();
  {
    float v = val_s[tid];
    int rank = 0;
    for (int m = 0; m < 128; ++m) {
      float vm = val_s[m];
      rank += (vm < v || (vm == v && m < tid)) ? 1 : 0;
    }
    stb_s[rank] = v; perm_s[rank] = tid;
  }
  __syncthreads();
  tb[tid] = stb_s[tid];
  if (tid < 96) {
    float s0  = stb_s[0];
    float tm0 = (s0 == INF) ? 1.0f : 0.5f * s0;
    float sa = 0.f, sb = 0.f;
#pragma unroll 8
    for (int j = 0; j < 128; ++j) {
      float on = (tm0 * w1_s[j] + b1_s[j] > 0.0f) ? 1.f : 0.f;
      float w2 = on * w2_s[j * 96 + tid];
      sa += w2 * w1_s[j]; sb += w2 * b1_s[j];
    }
    float b2v = b2[tid];
    At[tid] = sa; Bt[tid] = sb + b2v;
#pragma unroll 8
    for (int s = 0; s < 128; ++s) {
      int   j    = perm_s[s];
      float live = (stb_s[s] < INF) ? 1.f : 0.f;
      float sgn  = (w1_s[j] > 0.f) ? live : -live;
      float w2   = sgn * w2_s[j * 96 + tid];
      sa += w2 * w1_s[j]; sb += w2 * b1_s[j];
      At[(s + 1) * 96 + tid] = sa; Bt[(s + 1) * 96 + tid] = sb + b2v;
    }
  }
}

// ---------------------------------------------------------------------------
// K2 (fused): blocks [0,1161): qt table; blocks [1161,1417): iv + block hist.
// qt layout: byte(iv,c,k) = iv*16384 + (c>>4)*1024 + (k>>3)*256 + (c&15)*16
//            + (k&7)*2;  k = y (QA), 9+y (QB); k in [18,32) zeroed via y==0.
// ---------------------------------------------------------------------------
__global__ void k_mid(const float* __restrict__ Q, const float* __restrict__ At,
                      const float* __restrict__ Bt, const float* __restrict__ tbg,
                      const float* __restrict__ r,
                      unsigned short* __restrict__ qt,
                      unsigned short* __restrict__ ivz,
                      unsigned short* __restrict__ bh) {
  const int tid = threadIdx.x;
  if (blockIdx.x < NQTBLK) {
    __shared__ float at_s[96], bt_s[96];
    const int iv = blockIdx.x % 129, y = blockIdx.x / 129, c = tid;
    if (c < 96) { at_s[c] = At[iv * 96 + c]; bt_s[c] = Bt[iv * 96 + c]; }
    __syncthreads();
    const float* q = Q + (size_t)c * 864 + y * 96;
    float qa = 0.f, qb = 0.f;
#pragma unroll
    for (int w4 = 0; w4 < 24; ++w4) {
      float4 qv = *(const float4*)(q + w4 * 4);
      qa += qv.x * at_s[w4*4+0] + qv.y * at_s[w4*4+1] + qv.z * at_s[w4*4+2] + qv.w * at_s[w4*4+3];
      qb += qv.x * bt_s[w4*4+0] + qv.y * bt_s[w4*4+1] + qv.z * bt_s[w4*4+2] + qv.w * bt_s[w4*4+3];
    }
    char* base = (char*)qt + (size_t)iv * 16384 + (c >> 4) * 1024 + (c & 15) * 16;
    const int ka = y, kb = 9 + y;
    *(unsigned short*)(base + (ka >> 3) * 256 + (ka & 7) * 2) = f2bf(qa);
    *(unsigned short*)(base + (kb >> 3) * 256 + (kb & 7) * 2) = f2bf(qb);
    if (y == 0) {
#pragma unroll
      for (int k = 18; k < 32; ++k)
        *(unsigned short*)(base + (k >> 3) * 256 + (k & 7) * 2) = 0;
    }
    return;
  }
  // ---- iv part: block bb handles points [bb*256, bb*256+256) ----
  __shared__ float tb_s[128];
  __shared__ unsigned int h_s[129];
  const int bb = blockIdx.x - NQTBLK;
  const int z = bb * 256 + tid;
  if (tid < 128) tb_s[tid] = tbg[tid];
  if (tid < 129) h_s[tid] = 0;
  __syncthreads();
  float rx = r[z * 3 + 0], ry = r[z * 3 + 1], rz = r[z * 3 + 2];
  float rad = sqrtf(rx * rx + ry * ry + rz * rz);
  int lo = 0, hi = 128;
  while (lo < hi) { int mid = (lo + hi) >> 1;
                    if (tb_s[mid] < rad) lo = mid + 1; else hi = mid; }
  ivz[z] = (unsigned short)(lo | (rad > 0.f ? 0 : 0x8000));
  atomicAdd(&h_s[lo], 1u);
  __syncthreads();
  if (tid < 129) bh[tid * 256 + bb] = (unsigned short)h_s[tid];  // bh[iv][block]
}

// ---------------------------------------------------------------------------
// K3: scan. 1 block, 256 thr. Produces boff[sb][iv] (sb = 1024-pt scatter
// block, 64 of them) and btab.
// ---------------------------------------------------------------------------
__global__ void k_scan(const unsigned short* __restrict__ bh,
                       unsigned int* __restrict__ boff, uint4* __restrict__ btab) {
  __shared__ unsigned int tot_s[129], st_s[130], eo_s[130];
  const int tid = threadIdx.x;
  if (tid < 129) {
    const uint4* p = (const uint4*)(bh + tid * 256);   // 256 u16 = 32 uint4
    unsigned s = 0;
#pragma unroll 8
    for (int i = 0; i < 32; ++i) {
      uint4 v = p[i];
      s += (v.x & 0xFFFFu) + (v.x >> 16) + (v.y & 0xFFFFu) + (v.y >> 16)
         + (v.z & 0xFFFFu) + (v.z >> 16) + (v.w & 0xFFFFu) + (v.w >> 16);
    }
    tot_s[tid] = s;
  }
  __syncthreads();
  if (tid == 0) {
    unsigned s = 0, e = 0;
    for (int i = 0; i < 129; ++i) {
      st_s[i] = s; eo_s[i] = e;
      s += tot_s[i]; e += (tot_s[i] + 63) >> 6;
    }
    st_s[129] = s; eo_s[129] = e;
  }
  __syncthreads();
  if (tid < 129) {   // per-(scatter-block, iv) cursor bases (4 hist blocks per sb)
    unsigned run = st_s[tid];
    for (int b = 0; b < 256; ++b) {
      if ((b & 3) == 0) boff[(b >> 2) * 132 + tid] = run;
      run += bh[tid * 256 + b];
    }
  }
  const unsigned total = eo_s[129];
  for (unsigned e = tid; e < NCHUNKS; e += 256) {
    uint4 ent = make_uint4(0, 0, 0, 0);
    if (e < total) {
      int lo = 0, hi = 128;
      while (lo < hi) { int mid = (lo + hi + 1) >> 1;
                        if (eo_s[mid] <= e) lo = mid; else hi = mid - 1; }
      unsigned chunk = e - eo_s[lo];
      unsigned cnt = tot_s[lo] - chunk * 64; if (cnt > 64) cnt = 64;
      ent = make_uint4((unsigned)lo, st_s[lo] + chunk * 64, cnt, 0);
    }
    btab[e] = ent;
  }
}

// ---------------------------------------------------------------------------
// K4: scatter via LDS cursors (no global atomics). 64 blocks x 1024 thr.
// ---------------------------------------------------------------------------
__global__ __launch_bounds__(1024)
void k_scatter(const unsigned short* __restrict__ ivz,
               const unsigned int* __restrict__ boff,
               unsigned int* __restrict__ perm) {
  __shared__ unsigned int cur_s[129];
  const int tid = threadIdx.x, bb = blockIdx.x;
  if (tid < 129) cur_s[tid] = boff[bb * 132 + tid];
  __syncthreads();
  const int z = bb * 1024 + tid;
  unsigned u = ivz[z];
  unsigned iv = u & 255u;
  unsigned pos = atomicAdd(&cur_s[iv], 1u);
  perm[pos] = (unsigned)z | ((u & 0x8000u) << 16);
}

// ---------------------------------------------------------------------------
// K5: output. grid NCHUNKS x 256 thr (4 waves). Block = one (iv, 64-pt chunk).
// T_s staged via global_load_lds; coef built in-thread; one K=32 MFMA pass;
// scatter-store 1KB rows. Conflict-free subtiled LDS on both operands.
// ---------------------------------------------------------------------------
__global__ __launch_bounds__(256)
void k_out(const float* __restrict__ r, const unsigned short* __restrict__ qt,
           const unsigned int* __restrict__ perm, const uint4* __restrict__ btab,
           const float* __restrict__ K0, float* __restrict__ out) {
  __shared__ unsigned short T_s[8192];     // 16 KB: [cb(16)][g(4)][c16(16)][e(8)]
  __shared__ unsigned short coef_s[2048];  //  4 KB: [rb(4)][g(4)][r16(16)][e(8)]
  __shared__ unsigned int z_s[64];
  __shared__ unsigned int mk_s[64];

  const uint4 ent = btab[blockIdx.x];
  const unsigned iv = ent.x, base = ent.y, cnt = ent.z;
  if (cnt == 0) return;

  const int tid  = threadIdx.x;
  const int lane = tid & 63;
  const int wave = tid >> 6;
  const int lg   = lane >> 4;
  const int l15  = lane & 15;

  // stage T[iv] (16 KB) via async global->LDS
  {
    const char* src = (const char*)qt + (size_t)iv * 16384 + wave * 1024 + lane * 16;
    char* dst = (char*)T_s + wave * 1024;
#pragma unroll
    for (int i = 0; i < 4; ++i) gl_lds16(src + i * 4096, dst + i * 4096);
  }

  // coef staging: thread j < 64 handles one point
  if (tid < 64) {
    const int j = tid;
    unsigned pz = perm[base + (j < (int)cnt ? j : 0)];
    unsigned z = pz & 0x7FFFFFFFu;
    z_s[j] = z; mk_s[j] = pz >> 31;
    const float* rg = r + (size_t)z * 3;
    float rx = rg[0], ry = rg[1], rz = rg[2];
    float rad = sqrtf(rx * rx + ry * ry + rz * rz);
    float inv = (rad > 0.f) ? (1.0f / rad) : 1.0f;
    float x = rx * inv, y = ry * inv, zc = rz * inv;
    const float SQ3 = 1.7320508075688772f, SQ5 = 2.2360679774997896f,
                SQ15 = 3.872983346207417f;
    float ys[9];
    ys[0] = 1.f;
    ys[1] = SQ3 * y;  ys[2] = SQ3 * zc;  ys[3] = SQ3 * x;
    ys[4] = SQ15 * x * y;  ys[5] = SQ15 * y * zc;
    ys[6] = 0.5f * SQ5 * (3.f * zc * zc - 1.f);
    ys[7] = SQ15 * x * zc;
    ys[8] = 0.5f * SQ15 * (x * x - y * y);
    float cf[18];
#pragma unroll
    for (int m = 0; m < 9; ++m) { cf[m] = ys[m] * rad; cf[9 + m] = ys[m]; }
    char* cbp = (char*)coef_s + (j >> 4) * 1024 + (j & 15) * 16;
#pragma unroll
    for (int g = 0; g < 4; ++g)
#pragma unroll
      for (int p = 0; p < 4; ++p) {
        const int k0 = g * 8 + p * 2, k1 = k0 + 1;
        float v0 = (k0 < 18) ? cf[k0] : 0.f;
        float v1 = (k1 < 18) ? cf[k1] : 0.f;
        *(unsigned int*)(cbp + g * 256 + p * 4) = pack2(v0, v1);
      }
  }
  __syncthreads();   // T_s (vmcnt) + coef_s published

  // MFMA: wave handles rows [wave*16, wave*16+16) x all 256 cols
  fx4 acc[16];
#pragma unroll
  for (int cb2 = 0; cb2 < 16; ++cb2)
#pragma unroll
    for (int e = 0; e < 4; ++e) acc[cb2][e] = 0.f;

  const bfrag a = *(const bfrag*)((char*)coef_s + wave * 1024 + lg * 256 + l15 * 16);
#pragma unroll
  for (int cb2 = 0; cb2 < 16; ++cb2) {
    const bfrag b = *(const bfrag*)((char*)T_s + cb2 * 1024 + lg * 256 + l15 * 16);
    acc[cb2] = __builtin_amdgcn_mfma_f32_16x16x32_bf16(a, b, acc[cb2], 0, 0, 0);
  }

  // store: C/D 16x16 map: col = lane&15, row = (lane>>4)*4 + q
  float k0v[16];
#pragma unroll
  for (int cb2 = 0; cb2 < 16; ++cb2) k0v[cb2] = K0[cb2 * 16 + l15];
#pragma unroll
  for (int q = 0; q < 4; ++q) {
    const int br = wave * 16 + lg * 4 + q;
    if (br < (int)cnt) {
      const unsigned z = z_s[br];
      const bool mq = mk_s[br] != 0;
      float* ob = out + (size_t)z * 256 + l15;
#pragma unroll
      for (int cb2 = 0; cb2 < 16; ++cb2)
        ob[cb2 * 16] = mq ? k0v[cb2] : acc[cb2][q];
    }
  }
}

// ---------------------------------------------------------------------------
extern "C" void kernel_launch(void* const* d_in, const int* in_sizes, int n_in,
                              void* d_out, int out_size, void* d_ws, size_t ws_size,
                              hipStream_t stream) {
  const float* r  = (const float*)d_in[0];
  const float* Q  = (const float*)d_in[1];
  const float* W1 = (const float*)d_in[2];
  const float* b1 = (const float*)d_in[3];
  const float* W2 = (const float*)d_in[4];
  const float* b2 = (const float*)d_in[5];
  const float* K0 = (const float*)d_in[6];
  float* out = (float*)d_out;
  char* ws = (char*)d_ws;
  float* tb = (float*)(ws + WS_TB);
  float* At = (float*)(ws + WS_AT);
  float* Bt = (float*)(ws + WS_BT);
  unsigned short* qt  = (unsigned short*)(ws + WS_QT);
  unsigned short* ivz = (unsigned short*)(ws + WS_IVZ);
  unsigned int* permb = (unsigned int*)(ws + WS_PERM);
  unsigned short* bh  = (unsigned short*)(ws + WS_BH);
  unsigned int* boff  = (unsigned int*)(ws + WS_BOFF);
  uint4* btab         = (uint4*)(ws + WS_BTAB);

  hipLaunchKernelGGL(k_tables, dim3(1), dim3(128), 0, stream, W1, b1, W2, b2, tb, At, Bt);
  hipLaunchKernelGGL(k_mid, dim3(NQTBLK + 256), dim3(256), 0, stream,
                     Q, At, Bt, tb, r, qt, ivz, bh);
  hipLaunchKernelGGL(k_scan, dim3(1), dim3(256), 0, stream, bh, boff, btab);
  hipLaunchKernelGGL(k_scatter, dim3(64), dim3(1024), 0, stream, ivz, boff, permb);
  hipLaunchKernelGGL(k_out, dim3(NCHUNKS), dim3(256), 0, stream, r, qt, permb, btab, K0, out);
}

// Round 10
// 62.599 us; speedup vs baseline: 3.7853x; 1.2310x over previous
//
#include <hip/hip_runtime.h>
#include <hip/hip_bf16.h>

// ---------------------------------------------------------------------------
// Reformulation: Rad[z,:] = t*A[iv] + B[iv] (piecewise-linear MLP) =>
//   C[z,c] = sum_m coef[z,m] * T[iv_z][m][c],  K = 18 (not 864)
//   coef[m<9] = Ysh[y=m]*t, coef[9+y] = Ysh[y]
//   T[iv][y][c] = sum_w A[iv,w]*Q[c,y,w];  T[iv][9+y][c] = sum_w B[iv,w]*Q[c,y,w]
// Counting sort by iv, deterministic, no global atomics. Round-10: pipeline
// collapsed 5 -> 3 launches:
//   K1: [tables block || 256 iv-blocks]  (iv = count of hinges < rad, no sort
//       dependency; bh stored [block][iv] coalesced)
//   K2: [1161 qt blocks || 256 scatter blocks (per-block redundant scan,
//       block 0 writes btab)]
//   K3: k_out (64-pt uniform-iv chunks, 16x16x32 MFMA, row stores)
// ws peak 2,692,368 B < 2,708,240 proven safe (round 6).
// ---------------------------------------------------------------------------

typedef __attribute__((ext_vector_type(8))) short bfrag;   // 8 x bf16
typedef __attribute__((ext_vector_type(4))) float fx4;     // 16x16 accum

// workspace byte offsets
#define WS_AT   512         // f32[129*96] = 49536, ends 50048
#define WS_BT   50048       // f32[129*96] = 49536, ends 99584
#define WS_QT   99584       // bf16[129][16384B] = 2113536, ends 2213120
#define WS_IVZ  2213120     // u16[65536] = 131072, ends 2344192
#define WS_PERM 2344192     // u32[65536] = 262144, ends 2606336
#define WS_BH   2606336     // u16[256][132] = 67584, ends 2673920
#define WS_BTAB 2673920     // uint4[1153] = 18448, ends 2692368 (peak)
#define NCHUNKS 1153        // 65536/64 + 129 upper bound
#define NQTBLK  1161        // 129 iv * 9 y

__device__ inline unsigned short f2bf(float f) {   // RNE float->bf16
  union { float f; unsigned int u; } v; v.f = f;
  unsigned int r = v.u + 0x7FFFu + ((v.u >> 16) & 1u);
  return (unsigned short)(r >> 16);
}
__device__ inline unsigned int pack2(float a, float b) {
  return (unsigned int)f2bf(a) | ((unsigned int)f2bf(b) << 16);
}
__device__ inline void gl_lds16(const void* g, void* l) {
  __builtin_amdgcn_global_load_lds(
      (const __attribute__((address_space(1))) unsigned int*)g,
      (__attribute__((address_space(3))) unsigned int*)l, 16, 0, 0);
}

// ---------------------------------------------------------------------------
// K1: blocks [0,256): per-point iv (= count of valid hinges with tj < rad)
//     + per-block histogram bh[block][iv] (coalesced row).
//     block 256: piecewise-linear (A,B) tables via sorted hinge walk.
// ---------------------------------------------------------------------------
__global__ void k_pre(const float* __restrict__ W1, const float* __restrict__ b1,
                      const float* __restrict__ W2, const float* __restrict__ b2,
                      const float* __restrict__ r,
                      float* __restrict__ At, float* __restrict__ Bt,
                      unsigned short* __restrict__ ivz,
                      unsigned short* __restrict__ bh) {
  const int tid = threadIdx.x;
  const float INF = __builtin_inff();

  if (blockIdx.x == 256) {
    // ----- tables block -----
    __shared__ float w2_s[128 * 96];
    __shared__ float val_s[128], stb_s[128], w1_s[128], b1_s[128];
    __shared__ int   perm_s[128];
    for (int i = tid; i < 128 * 96; i += 256) w2_s[i] = W2[i];
    if (tid < 128) {
      float w1 = W1[tid], b1v = b1[tid];
      w1_s[tid] = w1; b1_s[tid] = b1v;
      float tj = -b1v / w1;
      bool valid = (w1 != 0.0f) && (tj > 0.0f);
      val_s[tid] = valid ? tj : INF;
    }
    __syncthreads();
    if (tid < 128) {
      float v = val_s[tid];
      int rank = 0;
      for (int m = 0; m < 128; ++m) {
        float vm = val_s[m];
        rank += (vm < v || (vm == v && m < tid)) ? 1 : 0;
      }
      stb_s[rank] = v; perm_s[rank] = tid;
    }
    __syncthreads();
    if (tid < 96) {
      float s0  = stb_s[0];
      float tm0 = (s0 == INF) ? 1.0f : 0.5f * s0;
      float sa = 0.f, sb = 0.f;
#pragma unroll 8
      for (int j = 0; j < 128; ++j) {
        float on = (tm0 * w1_s[j] + b1_s[j] > 0.0f) ? 1.f : 0.f;
        float w2 = on * w2_s[j * 96 + tid];
        sa += w2 * w1_s[j]; sb += w2 * b1_s[j];
      }
      float b2v = b2[tid];
      At[tid] = sa; Bt[tid] = sb + b2v;
#pragma unroll 8
      for (int s = 0; s < 128; ++s) {
        int   j    = perm_s[s];
        float live = (stb_s[s] < INF) ? 1.f : 0.f;
        float sgn  = (w1_s[j] > 0.f) ? live : -live;
        float w2   = sgn * w2_s[j * 96 + tid];
        sa += w2 * w1_s[j]; sb += w2 * b1_s[j];
        At[(s + 1) * 96 + tid] = sa; Bt[(s + 1) * 96 + tid] = sb + b2v;
      }
    }
    return;
  }

  // ----- iv block bb: points [bb*256, bb*256+256) -----
  __shared__ float tj_s[128];
  __shared__ unsigned int h_s[129];
  const int bb = blockIdx.x;
  if (tid < 128) {
    float w1 = W1[tid], b1v = b1[tid];
    float tj = -b1v / w1;
    bool valid = (w1 != 0.0f) && (tj > 0.0f);
    tj_s[tid] = valid ? tj : INF;
  }
  if (tid < 129) h_s[tid] = 0;
  __syncthreads();
  const int z = bb * 256 + tid;
  float rx = r[z * 3 + 0], ry = r[z * 3 + 1], rz = r[z * 3 + 2];
  float rad = sqrtf(rx * rx + ry * ry + rz * rz);
  int cnt = 0;
#pragma unroll 16
  for (int j = 0; j < 128; ++j) cnt += (tj_s[j] < rad) ? 1 : 0;
  ivz[z] = (unsigned short)(cnt | (rad > 0.f ? 0 : 0x8000));
  atomicAdd(&h_s[cnt], 1u);
  __syncthreads();
  if (tid < 129) bh[bb * 132 + tid] = (unsigned short)h_s[tid];
}

// ---------------------------------------------------------------------------
// K2: blocks [0,1161): qt table. blocks [1161,1417): scatter block bb
//     (per-block redundant scan of bh rows; block 0 also emits btab).
// qt layout: byte(iv,c,k) = iv*16384 + (c>>4)*1024 + (k>>3)*256 + (c&15)*16
//            + (k&7)*2;  k = y (QA), 9+y (QB); k in [18,32) zeroed via y==0.
// ---------------------------------------------------------------------------
__global__ void k_mid(const float* __restrict__ Q, const float* __restrict__ At,
                      const float* __restrict__ Bt,
                      const unsigned short* __restrict__ ivz,
                      const unsigned short* __restrict__ bh,
                      unsigned short* __restrict__ qt,
                      unsigned int* __restrict__ perm,
                      uint4* __restrict__ btab) {
  const int tid = threadIdx.x;
  if (blockIdx.x < NQTBLK) {
    __shared__ float at_s[96], bt_s[96];
    const int iv = blockIdx.x % 129, y = blockIdx.x / 129, c = tid;
    if (c < 96) { at_s[c] = At[iv * 96 + c]; bt_s[c] = Bt[iv * 96 + c]; }
    __syncthreads();
    const float* q = Q + (size_t)c * 864 + y * 96;
    float qa = 0.f, qb = 0.f;
#pragma unroll
    for (int w4 = 0; w4 < 24; ++w4) {
      float4 qv = *(const float4*)(q + w4 * 4);
      qa += qv.x * at_s[w4*4+0] + qv.y * at_s[w4*4+1] + qv.z * at_s[w4*4+2] + qv.w * at_s[w4*4+3];
      qb += qv.x * bt_s[w4*4+0] + qv.y * bt_s[w4*4+1] + qv.z * bt_s[w4*4+2] + qv.w * bt_s[w4*4+3];
    }
    char* base = (char*)qt + (size_t)iv * 16384 + (c >> 4) * 1024 + (c & 15) * 16;
    const int ka = y, kb = 9 + y;
    *(unsigned short*)(base + (ka >> 3) * 256 + (ka & 7) * 2) = f2bf(qa);
    *(unsigned short*)(base + (kb >> 3) * 256 + (kb & 7) * 2) = f2bf(qb);
    if (y == 0) {
#pragma unroll
      for (int k = 18; k < 32; ++k)
        *(unsigned short*)(base + (k >> 3) * 256 + (k & 7) * 2) = 0;
    }
    return;
  }
  // ----- scatter block bb: points [bb*256, bb*256+256) -----
  __shared__ unsigned int tot_s[129], pre_s[129], st_s[130], eo_s[130];
  __shared__ unsigned int cur_s[129];
  const int bb = blockIdx.x - NQTBLK;    // 0..255
  if (tid < 129) {
    unsigned tot = 0, pre = 0;
#pragma unroll 8
    for (int b = 0; b < 256; ++b) {
      unsigned v = bh[b * 132 + tid];
      tot += v;
      pre += (b < bb) ? v : 0;
    }
    tot_s[tid] = tot; pre_s[tid] = pre;
  }
  __syncthreads();
  if (tid == 0) {
    unsigned s = 0, e = 0;
    for (int i = 0; i < 129; ++i) {
      st_s[i] = s; eo_s[i] = e;
      s += tot_s[i]; e += (tot_s[i] + 63) >> 6;
    }
    st_s[129] = s; eo_s[129] = e;
  }
  __syncthreads();
  if (tid < 129) cur_s[tid] = st_s[tid] + pre_s[tid];
  __syncthreads();
  const int z = bb * 256 + tid;
  unsigned u = ivz[z];
  unsigned iv = u & 255u;
  unsigned pos = atomicAdd(&cur_s[iv], 1u);
  perm[pos] = (unsigned)z | ((u & 0x8000u) << 16);
  if (bb == 0) {
    const unsigned total = eo_s[129];
    for (unsigned e = tid; e < NCHUNKS; e += 256) {
      uint4 ent = make_uint4(0, 0, 0, 0);
      if (e < total) {
        int lo = 0, hi = 128;
        while (lo < hi) { int mid = (lo + hi + 1) >> 1;
                          if (eo_s[mid] <= e) lo = mid; else hi = mid - 1; }
        unsigned chunk = e - eo_s[lo];
        unsigned cnt = tot_s[lo] - chunk * 64; if (cnt > 64) cnt = 64;
        ent = make_uint4((unsigned)lo, st_s[lo] + chunk * 64, cnt, 0);
      }
      btab[e] = ent;
    }
  }
}

// ---------------------------------------------------------------------------
// K3: output. grid NCHUNKS x 256 thr (4 waves). Block = one (iv, 64-pt chunk).
// ---------------------------------------------------------------------------
__global__ __launch_bounds__(256)
void k_out(const float* __restrict__ r, const unsigned short* __restrict__ qt,
           const unsigned int* __restrict__ perm, const uint4* __restrict__ btab,
           const float* __restrict__ K0, float* __restrict__ out) {
  __shared__ unsigned short T_s[8192];     // 16 KB: [cb(16)][g(4)][c16(16)][e(8)]
  __shared__ unsigned short coef_s[2048];  //  4 KB: [rb(4)][g(4)][r16(16)][e(8)]
  __shared__ unsigned int z_s[64];
  __shared__ unsigned int mk_s[64];

  const uint4 ent = btab[blockIdx.x];
  const unsigned iv = ent.x, base = ent.y, cnt = ent.z;
  if (cnt == 0) return;

  const int tid  = threadIdx.x;
  const int lane = tid & 63;
  const int wave = tid >> 6;
  const int lg   = lane >> 4;
  const int l15  = lane & 15;

  // stage T[iv] (16 KB) via async global->LDS
  {
    const char* src = (const char*)qt + (size_t)iv * 16384 + wave * 1024 + lane * 16;
    char* dst = (char*)T_s + wave * 1024;
#pragma unroll
    for (int i = 0; i < 4; ++i) gl_lds16(src + i * 4096, dst + i * 4096);
  }

  // coef staging: thread j < 64 handles one point
  if (tid < 64) {
    const int j = tid;
    unsigned pz = perm[base + (j < (int)cnt ? j : 0)];
    unsigned z = pz & 0x7FFFFFFFu;
    z_s[j] = z; mk_s[j] = pz >> 31;
    const float* rg = r + (size_t)z * 3;
    float rx = rg[0], ry = rg[1], rz = rg[2];
    float rad = sqrtf(rx * rx + ry * ry + rz * rz);
    float inv = (rad > 0.f) ? (1.0f / rad) : 1.0f;
    float x = rx * inv, y = ry * inv, zc = rz * inv;
    const float SQ3 = 1.7320508075688772f, SQ5 = 2.2360679774997896f,
                SQ15 = 3.872983346207417f;
    float ys[9];
    ys[0] = 1.f;
    ys[1] = SQ3 * y;  ys[2] = SQ3 * zc;  ys[3] = SQ3 * x;
    ys[4] = SQ15 * x * y;  ys[5] = SQ15 * y * zc;
    ys[6] = 0.5f * SQ5 * (3.f * zc * zc - 1.f);
    ys[7] = SQ15 * x * zc;
    ys[8] = 0.5f * SQ15 * (x * x - y * y);
    float cf[18];
#pragma unroll
    for (int m = 0; m < 9; ++m) { cf[m] = ys[m] * rad; cf[9 + m] = ys[m]; }
    char* cbp = (char*)coef_s + (j >> 4) * 1024 + (j & 15) * 16;
#pragma unroll
    for (int g = 0; g < 4; ++g)
#pragma unroll
      for (int p = 0; p < 4; ++p) {
        const int k0 = g * 8 + p * 2, k1 = k0 + 1;
        float v0 = (k0 < 18) ? cf[k0] : 0.f;
        float v1 = (k1 < 18) ? cf[k1] : 0.f;
        *(unsigned int*)(cbp + g * 256 + p * 4) = pack2(v0, v1);
      }
  }
  __syncthreads();   // T_s (vmcnt) + coef_s published

  // MFMA: wave handles rows [wave*16, wave*16+16) x all 256 cols
  fx4 acc[16];
#pragma unroll
  for (int cb2 = 0; cb2 < 16; ++cb2)
#pragma unroll
    for (int e = 0; e < 4; ++e) acc[cb2][e] = 0.f;

  const bfrag a = *(const bfrag*)((char*)coef_s + wave * 1024 + lg * 256 + l15 * 16);
#pragma unroll
  for (int cb2 = 0; cb2 < 16; ++cb2) {
    const bfrag b = *(const bfrag*)((char*)T_s + cb2 * 1024 + lg * 256 + l15 * 16);
    acc[cb2] = __builtin_amdgcn_mfma_f32_16x16x32_bf16(a, b, acc[cb2], 0, 0, 0);
  }

  // store: C/D 16x16 map: col = lane&15, row = (lane>>4)*4 + q
  float k0v[16];
#pragma unroll
  for (int cb2 = 0; cb2 < 16; ++cb2) k0v[cb2] = K0[cb2 * 16 + l15];
#pragma unroll
  for (int q = 0; q < 4; ++q) {
    const int br = wave * 16 + lg * 4 + q;
    if (br < (int)cnt) {
      const unsigned z = z_s[br];
      const bool mq = mk_s[br] != 0;
      float* ob = out + (size_t)z * 256 + l15;
#pragma unroll
      for (int cb2 = 0; cb2 < 16; ++cb2)
        ob[cb2 * 16] = mq ? k0v[cb2] : acc[cb2][q];
    }
  }
}

// ---------------------------------------------------------------------------
extern "C" void kernel_launch(void* const* d_in, const int* in_sizes, int n_in,
                              void* d_out, int out_size, void* d_ws, size_t ws_size,
                              hipStream_t stream) {
  const float* r  = (const float*)d_in[0];
  const float* Q  = (const float*)d_in[1];
  const float* W1 = (const float*)d_in[2];
  const float* b1 = (const float*)d_in[3];
  const float* W2 = (const float*)d_in[4];
  const float* b2 = (const float*)d_in[5];
  const float* K0 = (const float*)d_in[6];
  float* out = (float*)d_out;
  char* ws = (char*)d_ws;
  float* At = (float*)(ws + WS_AT);
  float* Bt = (float*)(ws + WS_BT);
  unsigned short* qt  = (unsigned short*)(ws + WS_QT);
  unsigned short* ivz = (unsigned short*)(ws + WS_IVZ);
  unsigned int* permb = (unsigned int*)(ws + WS_PERM);
  unsigned short* bh  = (unsigned short*)(ws + WS_BH);
  uint4* btab         = (uint4*)(ws + WS_BTAB);

  hipLaunchKernelGGL(k_pre, dim3(257), dim3(256), 0, stream,
                     W1, b1, W2, b2, r, At, Bt, ivz, bh);
  hipLaunchKernelGGL(k_mid, dim3(NQTBLK + 256), dim3(256), 0, stream,
                     Q, At, Bt, ivz, bh, qt, permb, btab);
  hipLaunchKernelGGL(k_out, dim3(NCHUNKS), dim3(256), 0, stream,
                     r, qt, permb, btab, K0, out);
}

// Round 11
// 60.175 us; speedup vs baseline: 3.9378x; 1.0403x over previous
//
#include <hip/hip_runtime.h>
#include <hip/hip_bf16.h>

// ---------------------------------------------------------------------------
// Reformulation: Rad[z,:] = t*A[iv] + B[iv] (piecewise-linear MLP) =>
//   C[z,c] = sum_m coef[z,m] * T[iv_z][m][c],  K = 18 (not 864)
//   T[iv][y][c] = sum_w A[iv,w]*Q[c,y,w];  T[iv][9+y][c] = sum_w B[iv,w]*Q[c,y,w]
// Counting sort by iv, deterministic, no global atomics. Round-11:
//   K1 k_pre:  [256 iv-blocks || 129 PARALLEL table-blocks]  (serial walk gone;
//              each table block rank-sorts hinges, evaluates activity at the
//              interval midpoint t*, sums A/B directly; coalesced W2 reads)
//   K2 k_mid:  [1161 qt blocks (Q y-slice LDS-staged, coalesced; was the
//              uncoalesced L1-thrash hog) || 256 scatter blocks]
//   K3 k_out:  64-pt uniform-iv chunks, 16x16x32 MFMA, row stores.
// ws peak 2,692,368 B < 2,708,240 proven safe (round 6).
// ---------------------------------------------------------------------------

typedef __attribute__((ext_vector_type(8))) short bfrag;   // 8 x bf16
typedef __attribute__((ext_vector_type(4))) float fx4;     // 16x16 accum

// workspace byte offsets
#define WS_AT   512         // f32[129*96] = 49536, ends 50048
#define WS_BT   50048       // f32[129*96] = 49536, ends 99584
#define WS_QT   99584       // bf16[129][16384B] = 2113536, ends 2213120
#define WS_IVZ  2213120     // u16[65536] = 131072, ends 2344192
#define WS_PERM 2344192     // u32[65536] = 262144, ends 2606336
#define WS_BH   2606336     // u16[256][132] = 67584, ends 2673920
#define WS_BTAB 2673920     // uint4[1153] = 18448, ends 2692368 (peak)
#define NCHUNKS 1153
#define NQTBLK  1161        // 129 iv * 9 y

__device__ inline unsigned short f2bf(float f) {   // RNE float->bf16
  union { float f; unsigned int u; } v; v.f = f;
  unsigned int r = v.u + 0x7FFFu + ((v.u >> 16) & 1u);
  return (unsigned short)(r >> 16);
}
__device__ inline unsigned int pack2(float a, float b) {
  return (unsigned int)f2bf(a) | ((unsigned int)f2bf(b) << 16);
}
__device__ inline void gl_lds16(const void* g, void* l) {
  __builtin_amdgcn_global_load_lds(
      (const __attribute__((address_space(1))) unsigned int*)g,
      (__attribute__((address_space(3))) unsigned int*)l, 16, 0, 0);
}

// ---------------------------------------------------------------------------
// K1: blocks [0,256): per-point iv (count of valid hinges with tj < rad)
//     + per-block histogram bh[block][iv].
//     blocks [256,385): table block (iv = bid-256): direct parallel A/B.
// ---------------------------------------------------------------------------
__global__ void k_pre(const float* __restrict__ W1, const float* __restrict__ b1,
                      const float* __restrict__ W2, const float* __restrict__ b2,
                      const float* __restrict__ r,
                      float* __restrict__ At, float* __restrict__ Bt,
                      unsigned short* __restrict__ ivz,
                      unsigned short* __restrict__ bh) {
  const int tid = threadIdx.x;
  const float INF = __builtin_inff();

  if (blockIdx.x >= 256) {
    // ----- table block for interval tiv -----
    const int tiv = blockIdx.x - 256;              // 0..128
    __shared__ float w1_s[128], b1_s[128], val_s[128], stb_s[128];
    if (tid < 128) {
      float w1 = W1[tid], b1v = b1[tid];
      w1_s[tid] = w1; b1_s[tid] = b1v;
      float tj = -b1v / w1;
      bool valid = (w1 != 0.0f) && (tj > 0.0f);
      val_s[tid] = valid ? tj : INF;
    }
    __syncthreads();
    if (tid < 128) {                               // rank sort (stable)
      float v = val_s[tid];
      int rank = 0;
      for (int m = 0; m < 128; ++m) {
        float vm = val_s[m];
        rank += (vm < v || (vm == v && m < tid)) ? 1 : 0;
      }
      stb_s[rank] = v;
    }
    __syncthreads();
    if (tid < 96) {
      float lo_e = (tiv == 0) ? 0.f : stb_s[tiv - 1];
      float hi_e = (tiv < 128) ? stb_s[tiv] : INF;
      float tstar;
      if (lo_e < INF) tstar = (hi_e < INF) ? 0.5f * (lo_e + hi_e) : (lo_e + 1.0f);
      else            tstar = 0.f;                 // empty bucket; values unused
      float sa = 0.f, sb = 0.f;
#pragma unroll 8
      for (int j = 0; j < 128; ++j) {
        float on = (w1_s[j] * tstar + b1_s[j] > 0.0f) ? 1.f : 0.f;
        float w2 = on * W2[j * 96 + tid];          // coalesced across tid
        sa += w2 * w1_s[j]; sb += w2 * b1_s[j];
      }
      At[tiv * 96 + tid] = sa;
      Bt[tiv * 96 + tid] = sb + b2[tid];
    }
    return;
  }

  // ----- iv block bb: points [bb*256, bb*256+256) -----
  __shared__ float tj_s[128];
  __shared__ unsigned int h_s[129];
  const int bb = blockIdx.x;
  if (tid < 128) {
    float w1 = W1[tid], b1v = b1[tid];
    float tj = -b1v / w1;
    bool valid = (w1 != 0.0f) && (tj > 0.0f);
    tj_s[tid] = valid ? tj : INF;
  }
  if (tid < 129) h_s[tid] = 0;
  __syncthreads();
  const int z = bb * 256 + tid;
  float rx = r[z * 3 + 0], ry = r[z * 3 + 1], rz = r[z * 3 + 2];
  float rad = sqrtf(rx * rx + ry * ry + rz * rz);
  int cnt = 0;
#pragma unroll 16
  for (int j = 0; j < 128; ++j) cnt += (tj_s[j] < rad) ? 1 : 0;
  ivz[z] = (unsigned short)(cnt | (rad > 0.f ? 0 : 0x8000));
  atomicAdd(&h_s[cnt], 1u);
  __syncthreads();
  if (tid < 129) bh[bb * 132 + tid] = (unsigned short)h_s[tid];
}

// ---------------------------------------------------------------------------
// K2: blocks [0,1161): qt (iv,y) with LDS-staged Q slice (coalesced).
//     blocks [1161,1417): scatter (per-block redundant scan; block 0 -> btab).
// qt layout: byte(iv,c,k) = iv*16384 + (c>>4)*1024 + (k>>3)*256 + (c&15)*16
//            + (k&7)*2;  k = y (QA), 9+y (QB); k in [18,32) zeroed via y==0.
// ---------------------------------------------------------------------------
__global__ __launch_bounds__(256)
void k_mid(const float* __restrict__ Q, const float* __restrict__ At,
           const float* __restrict__ Bt,
           const unsigned short* __restrict__ ivz,
           const unsigned short* __restrict__ bh,
           unsigned short* __restrict__ qt,
           unsigned int* __restrict__ perm,
           uint4* __restrict__ btab) {
  __shared__ float smem[12800];                    // 51,200 B carved union
  const int tid = threadIdx.x;

  if (blockIdx.x < NQTBLK) {
    float* qs   = smem;                            // [128][97]
    float* at_s = smem + 128 * 97;                 // 96
    float* bt_s = at_s + 96;                       // 96
    const int iv = blockIdx.x % 129, y = blockIdx.x / 129;
    if (tid < 96) { at_s[tid] = At[iv * 96 + tid]; bt_s[tid] = Bt[iv * 96 + tid]; }
#pragma unroll
    for (int half = 0; half < 2; ++half) {
      __syncthreads();                             // qs reuse / at_s ready
      // stage 128 c-rows x 96 floats, coalesced float4 runs
      for (int i = tid; i < 128 * 24; i += 256) {
        const int c_loc = i / 24, f4 = i - c_loc * 24;
        float4 v = *(const float4*)(Q + (size_t)(half * 128 + c_loc) * 864 + y * 96 + f4 * 4);
        float* d = qs + c_loc * 97 + f4 * 4;
        d[0] = v.x; d[1] = v.y; d[2] = v.z; d[3] = v.w;
      }
      __syncthreads();
      if (tid < 128) {
        const int c = half * 128 + tid;
        const float* row = qs + tid * 97;
        float qa = 0.f, qb = 0.f;
#pragma unroll 8
        for (int w = 0; w < 96; ++w) {
          float qv = row[w];
          qa += qv * at_s[w]; qb += qv * bt_s[w];
        }
        char* base = (char*)qt + (size_t)iv * 16384 + (c >> 4) * 1024 + (c & 15) * 16;
        const int ka = y, kb = 9 + y;
        *(unsigned short*)(base + (ka >> 3) * 256 + (ka & 7) * 2) = f2bf(qa);
        *(unsigned short*)(base + (kb >> 3) * 256 + (kb & 7) * 2) = f2bf(qb);
        if (y == 0) {
#pragma unroll
          for (int k = 18; k < 32; ++k)
            *(unsigned short*)(base + (k >> 3) * 256 + (k & 7) * 2) = 0;
        }
      }
    }
    return;
  }

  // ----- scatter block bb: points [bb*256, bb*256+256) -----
  unsigned int* tot_s = (unsigned int*)smem;        // 129
  unsigned int* pre_s = tot_s + 129;                // 129
  unsigned int* st_s  = pre_s + 129;                // 130
  unsigned int* eo_s  = st_s + 130;                 // 130
  unsigned int* cur_s = eo_s + 130;                 // 129
  const int bb = blockIdx.x - NQTBLK;               // 0..255
  if (tid < 129) {
    unsigned tot = 0, pre = 0;
#pragma unroll 8
    for (int b = 0; b < 256; ++b) {
      unsigned v = bh[b * 132 + tid];
      tot += v;
      pre += (b < bb) ? v : 0;
    }
    tot_s[tid] = tot; pre_s[tid] = pre;
  }
  __syncthreads();
  if (tid == 0) {
    unsigned s = 0, e = 0;
    for (int i = 0; i < 129; ++i) {
      st_s[i] = s; eo_s[i] = e;
      s += tot_s[i]; e += (tot_s[i] + 63) >> 6;
    }
    st_s[129] = s; eo_s[129] = e;
  }
  __syncthreads();
  if (tid < 129) cur_s[tid] = st_s[tid] + pre_s[tid];
  __syncthreads();
  const int z = bb * 256 + tid;
  unsigned u = ivz[z];
  unsigned iv = u & 255u;
  unsigned pos = atomicAdd(&cur_s[iv], 1u);
  perm[pos] = (unsigned)z | ((u & 0x8000u) << 16);
  if (bb == 0) {
    const unsigned total = eo_s[129];
    for (unsigned e = tid; e < NCHUNKS; e += 256) {
      uint4 ent = make_uint4(0, 0, 0, 0);
      if (e < total) {
        int lo = 0, hi = 128;
        while (lo < hi) { int mid = (lo + hi + 1) >> 1;
                          if (eo_s[mid] <= e) lo = mid; else hi = mid - 1; }
        unsigned chunk = e - eo_s[lo];
        unsigned cnt = tot_s[lo] - chunk * 64; if (cnt > 64) cnt = 64;
        ent = make_uint4((unsigned)lo, st_s[lo] + chunk * 64, cnt, 0);
      }
      btab[e] = ent;
    }
  }
}

// ---------------------------------------------------------------------------
// K3: output. grid NCHUNKS x 256 thr (4 waves). Block = one (iv, 64-pt chunk).
// ---------------------------------------------------------------------------
__global__ __launch_bounds__(256)
void k_out(const float* __restrict__ r, const unsigned short* __restrict__ qt,
           const unsigned int* __restrict__ perm, const uint4* __restrict__ btab,
           const float* __restrict__ K0, float* __restrict__ out) {
  __shared__ unsigned short T_s[8192];     // 16 KB: [cb(16)][g(4)][c16(16)][e(8)]
  __shared__ unsigned short coef_s[2048];  //  4 KB: [rb(4)][g(4)][r16(16)][e(8)]
  __shared__ unsigned int z_s[64];
  __shared__ unsigned int mk_s[64];

  const uint4 ent = btab[blockIdx.x];
  const unsigned iv = ent.x, base = ent.y, cnt = ent.z;
  if (cnt == 0) return;

  const int tid  = threadIdx.x;
  const int lane = tid & 63;
  const int wave = tid >> 6;
  const int lg   = lane >> 4;
  const int l15  = lane & 15;

  // perm load first (latency overlaps the staging issues below)
  unsigned pz = 0;
  if (tid < 64) pz = perm[base + (tid < (int)cnt ? tid : 0)];

  // stage T[iv] (16 KB) via async global->LDS
  {
    const char* src = (const char*)qt + (size_t)iv * 16384 + wave * 1024 + lane * 16;
    char* dst = (char*)T_s + wave * 1024;
#pragma unroll
    for (int i = 0; i < 4; ++i) gl_lds16(src + i * 4096, dst + i * 4096);
  }

  // coef staging: thread j < 64 handles one point
  if (tid < 64) {
    const int j = tid;
    unsigned z = pz & 0x7FFFFFFFu;
    z_s[j] = z; mk_s[j] = pz >> 31;
    const float* rg = r + (size_t)z * 3;
    float rx = rg[0], ry = rg[1], rz = rg[2];
    float rad = sqrtf(rx * rx + ry * ry + rz * rz);
    float inv = (rad > 0.f) ? (1.0f / rad) : 1.0f;
    float x = rx * inv, y = ry * inv, zc = rz * inv;
    const float SQ3 = 1.7320508075688772f, SQ5 = 2.2360679774997896f,
                SQ15 = 3.872983346207417f;
    float ys[9];
    ys[0] = 1.f;
    ys[1] = SQ3 * y;  ys[2] = SQ3 * zc;  ys[3] = SQ3 * x;
    ys[4] = SQ15 * x * y;  ys[5] = SQ15 * y * zc;
    ys[6] = 0.5f * SQ5 * (3.f * zc * zc - 1.f);
    ys[7] = SQ15 * x * zc;
    ys[8] = 0.5f * SQ15 * (x * x - y * y);
    float cf[18];
#pragma unroll
    for (int m = 0; m < 9; ++m) { cf[m] = ys[m] * rad; cf[9 + m] = ys[m]; }
    char* cbp = (char*)coef_s + (j >> 4) * 1024 + (j & 15) * 16;
#pragma unroll
    for (int g = 0; g < 4; ++g)
#pragma unroll
      for (int p = 0; p < 4; ++p) {
        const int k0 = g * 8 + p * 2, k1 = k0 + 1;
        float v0 = (k0 < 18) ? cf[k0] : 0.f;
        float v1 = (k1 < 18) ? cf[k1] : 0.f;
        *(unsigned int*)(cbp + g * 256 + p * 4) = pack2(v0, v1);
      }
  }
  __syncthreads();   // T_s (vmcnt) + coef_s published

  // MFMA: wave handles rows [wave*16, wave*16+16) x all 256 cols
  fx4 acc[16];
#pragma unroll
  for (int cb2 = 0; cb2 < 16; ++cb2)
#pragma unroll
    for (int e = 0; e < 4; ++e) acc[cb2][e] = 0.f;

  const bfrag a = *(const bfrag*)((char*)coef_s + wave * 1024 + lg * 256 + l15 * 16);
#pragma unroll
  for (int cb2 = 0; cb2 < 16; ++cb2) {
    const bfrag b = *(const bfrag*)((char*)T_s + cb2 * 1024 + lg * 256 + l15 * 16);
    acc[cb2] = __builtin_amdgcn_mfma_f32_16x16x32_bf16(a, b, acc[cb2], 0, 0, 0);
  }

  // store: C/D 16x16 map: col = lane&15, row = (lane>>4)*4 + q
  float k0v[16];
#pragma unroll
  for (int cb2 = 0; cb2 < 16; ++cb2) k0v[cb2] = K0[cb2 * 16 + l15];
#pragma unroll
  for (int q = 0; q < 4; ++q) {
    const int br = wave * 16 + lg * 4 + q;
    if (br < (int)cnt) {
      const unsigned z = z_s[br];
      const bool mq = mk_s[br] != 0;
      float* ob = out + (size_t)z * 256 + l15;
#pragma unroll
      for (int cb2 = 0; cb2 < 16; ++cb2)
        ob[cb2 * 16] = mq ? k0v[cb2] : acc[cb2][q];
    }
  }
}

// ---------------------------------------------------------------------------
extern "C" void kernel_launch(void* const* d_in, const int* in_sizes, int n_in,
                              void* d_out, int out_size, void* d_ws, size_t ws_size,
                              hipStream_t stream) {
  const float* r  = (const float*)d_in[0];
  const float* Q  = (const float*)d_in[1];
  const float* W1 = (const float*)d_in[2];
  const float* b1 = (const float*)d_in[3];
  const float* W2 = (const float*)d_in[4];
  const float* b2 = (const float*)d_in[5];
  const float* K0 = (const float*)d_in[6];
  float* out = (float*)d_out;
  char* ws = (char*)d_ws;
  float* At = (float*)(ws + WS_AT);
  float* Bt = (float*)(ws + WS_BT);
  unsigned short* qt  = (unsigned short*)(ws + WS_QT);
  unsigned short* ivz = (unsigned short*)(ws + WS_IVZ);
  unsigned int* permb = (unsigned int*)(ws + WS_PERM);
  unsigned short* bh  = (unsigned short*)(ws + WS_BH);
  uint4* btab         = (uint4*)(ws + WS_BTAB);

  hipLaunchKernelGGL(k_pre, dim3(385), dim3(256), 0, stream,
                     W1, b1, W2, b2, r, At, Bt, ivz, bh);
  hipLaunchKernelGGL(k_mid, dim3(NQTBLK + 256), dim3(256), 0, stream,
                     Q, At, Bt, ivz, bh, qt, permb, btab);
  hipLaunchKernelGGL(k_out, dim3(NCHUNKS), dim3(256), 0, stream,
                     r, qt, permb, btab, K0, out);
}